// Round 7
// baseline (117.992 us; speedup 1.0000x reference)
//
#include <hip/hip_runtime.h>
#include <hip/hip_bf16.h>

typedef __attribute__((ext_vector_type(8))) short short8;
typedef __attribute__((ext_vector_type(4))) float f32x4;

#define NB 8
#define LQ 2048
#define LK 2048
#define DIN 1024
#define MROWS (NB * LQ)   // 16384

static constexpr float KSCALE = 0.022097086912079608f; // 1/sqrt(2048)

__device__ __forceinline__ ushort f2bf(float f) {
    union { float f; unsigned int u; } v; v.f = f;
    unsigned int r = v.u + 0x7FFFu + ((v.u >> 16) & 1u);   // RNE
    return (ushort)(r >> 16);
}
__device__ __forceinline__ float bf2f(ushort u) {
    union { unsigned int u; float f; } v; v.u = ((unsigned int)u) << 16;
    return v.f;
}
__device__ __forceinline__ unsigned pk2(float lo, float hi) {
    __hip_bfloat162 h = __float22bfloat162_rn(float2{lo, hi});   // v_cvt_pk_bf16_f32
    union { __hip_bfloat162 h; unsigned u; } c; c.h = h; return c.u;
}
__device__ __forceinline__ short8 cvt8(float4 lo, float4 hi) {   // 8 fp32 -> bf16x8
    union { short8 s; unsigned u[4]; } r;
    r.u[0] = pk2(lo.x, lo.y);
    r.u[1] = pk2(lo.z, lo.w);
    r.u[2] = pk2(hi.x, hi.y);
    r.u[3] = pk2(hi.z, hi.w);
    return r.s;
}

// ---------------------------------------------------------------------------
// prep: Wt[p][n][k] = bf16(W_p[k][n])  (transpose+convert, LDS tiled)
// ---------------------------------------------------------------------------
__global__ __launch_bounds__(256) void prep_kernel(
    const float* __restrict__ Wq, const float* __restrict__ Wk,
    const float* __restrict__ Wv, ushort* __restrict__ Wt)
{
    const float* W = (blockIdx.z == 0) ? Wq : (blockIdx.z == 1) ? Wk : Wv;
    ushort* O = Wt + (size_t)blockIdx.z * 128 * 1024;
    const int k0 = blockIdx.x * 64, n0 = blockIdx.y * 64;
    __shared__ float tile[64][65];
    const int t = threadIdx.x;
    {
        const int r = t >> 4, c = (t & 15) * 4;
        #pragma unroll
        for (int i = 0; i < 4; ++i) {
            float4 v = *(const float4*)&W[(size_t)(k0 + r + i * 16) * 128 + n0 + c];
            tile[r + i * 16][c + 0] = v.x; tile[r + i * 16][c + 1] = v.y;
            tile[r + i * 16][c + 2] = v.z; tile[r + i * 16][c + 3] = v.w;
        }
    }
    __syncthreads();
    {
        const int n = t >> 2, kc = (t & 3) * 16;
        ushort tmp[16];
        #pragma unroll
        for (int j = 0; j < 16; ++j) tmp[j] = f2bf(tile[kc + j][n]);
        *(uint4*)&O[(size_t)(n0 + n) * 1024 + k0 + kc]     = *(uint4*)&tmp[0];
        *(uint4*)&O[(size_t)(n0 + n) * 1024 + k0 + kc + 8] = *(uint4*)&tmp[8];
    }
}

// ---------------------------------------------------------------------------
// proj: Y = bf16(relu(X[16384,1024] @ W + b))
// ZERO-BARRIER wave-streaming: each wave owns a 32x64 output tile, loads its
// A/B MFMA fragments directly from global (per-lane, fragment-shaped), X
// cvt'd fp32->bf16 in-register. 2-deep named-set rotation; issue order
// PINNED with sched_barrier(0) after every phase (fixes R5's load-sinking:
// VGPR=52 proved the prefetch sets were dead). Full K unroll -> immediate
// offsets. Waves self-schedule; bound = L2 BW + VALU cvt, no sync stalls.
// 64x128 tile/block, grid (256,3), 4 waves (2x2 of 32x64). LDS epilogue only.
// ---------------------------------------------------------------------------
__global__ __launch_bounds__(256, 3) void proj_kernel(
    const float* __restrict__ Xq, const float* __restrict__ bq,
    const float* __restrict__ Xk, const float* __restrict__ bk,
    const float* __restrict__ Xv, const float* __restrict__ bv,
    const ushort* __restrict__ Wt,
    ushort* __restrict__ qp, ushort* __restrict__ kp, ushort* __restrict__ vp)
{
    const int p = blockIdx.y;
    const float* X; const float* bias; ushort* Y;
    if (p == 0)      { X = Xq; bias = bq; Y = qp; }
    else if (p == 1) { X = Xk; bias = bk; Y = kp; }
    else             { X = Xv; bias = bv; Y = vp; }
    const ushort* W = Wt + (size_t)p * 128 * 1024;

    __shared__ __align__(16) ushort Ys[64 * 128];   // 16 KB, epilogue only

    const int tid  = threadIdx.x;
    const int lane = tid & 63;
    const int w    = tid >> 6;
    const int wr   = (w >> 1) * 32;
    const int wc   = (w & 1) * 64;
    const int row0 = blockIdx.x * 64;

    const int col = lane & 15;          // fragment row/col within 16
    const int kg  = (lane >> 4) * 8;    // k-group 0,8,16,24

    // per-lane fragment base pointers (4-lane kg-groups cover 128B of a row)
    const float*  Xr0 = X + (size_t)(row0 + wr + col) * DIN + kg;
    const float*  Xr1 = Xr0 + (size_t)16 * DIN;
    const ushort* Wb0 = W + (size_t)(wc + col) * DIN + kg;
    const ushort* Wb1 = Wb0 + (size_t)16 * DIN;
    const ushort* Wb2 = Wb0 + (size_t)32 * DIN;
    const ushort* Wb3 = Wb0 + (size_t)48 * DIN;

    f32x4 acc[2][4];
    #pragma unroll
    for (int mi = 0; mi < 2; ++mi)
        #pragma unroll
        for (int ni = 0; ni < 4; ++ni)
            acc[mi][ni] = (f32x4){0.f, 0.f, 0.f, 0.f};

    // two named register sets (static indexing — rule #20)
    float4 Ax0, Ax1, Ax2, Ax3;  short8 Aw0, Aw1, Aw2, Aw3;
    float4 Bx0, Bx1, Bx2, Bx3;  short8 Bw0, Bw1, Bw2, Bw3;

#define SB() __builtin_amdgcn_sched_barrier(0)

#define LOAD_SET(s, ko) do {                                                  \
    s##x0 = *(const float4*)&Xr0[(ko)];                                       \
    s##x1 = *(const float4*)&Xr0[(ko) + 4];                                   \
    s##x2 = *(const float4*)&Xr1[(ko)];                                       \
    s##x3 = *(const float4*)&Xr1[(ko) + 4];                                   \
    s##w0 = *(const short8*)&Wb0[(ko)];                                       \
    s##w1 = *(const short8*)&Wb1[(ko)];                                       \
    s##w2 = *(const short8*)&Wb2[(ko)];                                       \
    s##w3 = *(const short8*)&Wb3[(ko)];                                       \
} while (0)

#define COMP_SET(s) do {                                                      \
    short8 af0 = cvt8(s##x0, s##x1);                                          \
    short8 af1 = cvt8(s##x2, s##x3);                                          \
    acc[0][0] = __builtin_amdgcn_mfma_f32_16x16x32_bf16(af0, s##w0, acc[0][0], 0, 0, 0); \
    acc[1][0] = __builtin_amdgcn_mfma_f32_16x16x32_bf16(af1, s##w0, acc[1][0], 0, 0, 0); \
    acc[0][1] = __builtin_amdgcn_mfma_f32_16x16x32_bf16(af0, s##w1, acc[0][1], 0, 0, 0); \
    acc[1][1] = __builtin_amdgcn_mfma_f32_16x16x32_bf16(af1, s##w1, acc[1][1], 0, 0, 0); \
    acc[0][2] = __builtin_amdgcn_mfma_f32_16x16x32_bf16(af0, s##w2, acc[0][2], 0, 0, 0); \
    acc[1][2] = __builtin_amdgcn_mfma_f32_16x16x32_bf16(af1, s##w2, acc[1][2], 0, 0, 0); \
    acc[0][3] = __builtin_amdgcn_mfma_f32_16x16x32_bf16(af0, s##w3, acc[0][3], 0, 0, 0); \
    acc[1][3] = __builtin_amdgcn_mfma_f32_16x16x32_bf16(af1, s##w3, acc[1][3], 0, 0, 0); \
} while (0)

    LOAD_SET(A, 0); SB();
    #pragma unroll
    for (int kc = 0; kc < DIN - 64; kc += 64) {
        LOAD_SET(B, kc + 32); SB();     // B in flight across COMP_SET(A)
        COMP_SET(A);         SB();
        LOAD_SET(A, kc + 64); SB();     // A in flight across COMP_SET(B)
        COMP_SET(B);         SB();
    }
    LOAD_SET(B, DIN - 32); SB();
    COMP_SET(A); SB();
    COMP_SET(B);

#undef LOAD_SET
#undef COMP_SET
#undef SB

    float bb[4];
    #pragma unroll
    for (int ni = 0; ni < 4; ++ni) bb[ni] = bias[wc + ni * 16 + col];

    const int orow4 = (lane >> 4) * 4;
    #pragma unroll
    for (int mi = 0; mi < 2; ++mi)
        #pragma unroll
        for (int ni = 0; ni < 4; ++ni)
            #pragma unroll
            for (int j = 0; j < 4; ++j) {
                float v = fmaxf(acc[mi][ni][j] + bb[ni], 0.f);
                const int rl = wr + mi * 16 + orow4 + j;
                const int cl = wc + ni * 16 + col;
                Ys[(rl * 128 + cl) ^ ((rl & 15) << 3)] = f2bf(v);
            }
    __syncthreads();

    {
        const int r = tid >> 2, c = (tid & 3) * 32;
        const int swz = (r & 15) << 3;
        ushort* Yg = Y + (size_t)(row0 + r) * 128 + c;
        #pragma unroll
        for (int j = 0; j < 4; ++j)
            *(uint4*)&Yg[j * 8] = *(const uint4*)&Ys[(r * 128 + c + j * 8) ^ swz];
    }
}

// ---------------------------------------------------------------------------
// ktv: per (batch, 64-row chunk): partial Mt_part[v][e] = sum_r v[r][v]*k[r][e]
// ---------------------------------------------------------------------------
__global__ __launch_bounds__(256) void ktv_kernel(
    const ushort* __restrict__ kp, const ushort* __restrict__ vp,
    ushort* __restrict__ part)
{
    const int b = blockIdx.y, chunk = blockIdx.x;
    const ushort* K = kp + ((size_t)b * LK + chunk * 64) * 128;
    const ushort* V = vp + ((size_t)b * LK + chunk * 64) * 128;
    ushort* P = part + ((size_t)(b * 32 + chunk)) * 16384;

    __shared__ __align__(16) ushort ks[64 * 128];
    __shared__ __align__(16) ushort vs[64 * 128];
    const int t = threadIdx.x;
    {
        const int r = t >> 2, cc = (t & 3) * 32;
        #pragma unroll
        for (int j = 0; j < 4; ++j) {
            *(uint4*)&ks[r * 128 + cc + j * 8] = *(const uint4*)&K[r * 128 + cc + j * 8];
            *(uint4*)&vs[r * 128 + cc + j * 8] = *(const uint4*)&V[r * 128 + cc + j * 8];
        }
    }
    __syncthreads();

    const int e0 = (t & 15) * 8;
    const int v0 = (t >> 4) * 8;
    float acc[8][8];
    #pragma unroll
    for (int i = 0; i < 8; ++i)
        #pragma unroll
        for (int j = 0; j < 8; ++j) acc[i][j] = 0.f;

    for (int r = 0; r < 64; ++r) {
        uint4 kf = *(const uint4*)&ks[r * 128 + e0];
        uint4 vf = *(const uint4*)&vs[r * 128 + v0];
        const ushort* kw = (const ushort*)&kf;
        const ushort* vw = (const ushort*)&vf;
        float ke[8], ve[8];
        #pragma unroll
        for (int j = 0; j < 8; ++j) { ke[j] = bf2f(kw[j]); ve[j] = bf2f(vw[j]); }
        #pragma unroll
        for (int i = 0; i < 8; ++i)
            #pragma unroll
            for (int j = 0; j < 8; ++j)
                acc[i][j] = fmaf(ve[i], ke[j], acc[i][j]);
    }

    #pragma unroll
    for (int i = 0; i < 8; ++i) {
        ushort tmp[8];
        #pragma unroll
        for (int j = 0; j < 8; ++j) tmp[j] = f2bf(acc[i][j]);
        *(uint4*)&P[(v0 + i) * 128 + e0] = *(uint4*)&tmp[0];
    }
}

// ---------------------------------------------------------------------------
// reduce: Mt[b][v*128+e] = bf16(KSCALE * sum_{c<32} part[b][c][v*128+e])
// ---------------------------------------------------------------------------
__global__ __launch_bounds__(256) void reduce_kernel(
    const ushort* __restrict__ part, ushort* __restrict__ Mt)
{
    const int g = blockIdx.x * 256 + threadIdx.x;
    const int b = g >> 14, idx = g & 16383;
    const ushort* P = part + (size_t)b * 32 * 16384 + idx;
    float s = 0.f;
    #pragma unroll
    for (int c = 0; c < 32; ++c) s += bf2f(P[(size_t)c * 16384]);
    Mt[g] = f2bf(s * KSCALE);
}

// ---------------------------------------------------------------------------
// qm: out[row][v] = sum_e qp[row][e] * Mt[b][v][e]
// ---------------------------------------------------------------------------
__global__ __launch_bounds__(256) void qm_kernel(
    const ushort* __restrict__ qp, const ushort* __restrict__ Mt,
    float* __restrict__ out)
{
    const int row0 = blockIdx.x * 64;
    const int b = row0 >> 11;
    const ushort* Q = qp + (size_t)row0 * 128;
    const ushort* M = Mt + (size_t)b * 16384;

    __shared__ __align__(16) ushort As[64 * 128];
    __shared__ __align__(16) ushort Bs[128 * 128];

    const int t = threadIdx.x;
    {
        const int r = t >> 2, cc = (t & 3) * 32;
        const int swz = (r & 15) << 3;
        #pragma unroll
        for (int j = 0; j < 4; ++j)
            *(uint4*)&As[(r * 128 + cc + j * 8) ^ swz] = *(const uint4*)&Q[r * 128 + cc + j * 8];
    }
    {
        const int r = t >> 1, cc = (t & 1) * 64;
        const int swz = (r & 15) << 3;
        #pragma unroll
        for (int j = 0; j < 8; ++j)
            *(uint4*)&Bs[(r * 128 + cc + j * 8) ^ swz] = *(const uint4*)&M[r * 128 + cc + j * 8];
    }
    __syncthreads();

    const int lane = t & 63;
    const int wcol = (t >> 6) * 32;
    const int col  = lane & 15;
    const int kgrp = (lane >> 4) * 8;
    const int fswz = col << 3;

    f32x4 acc[4][2];
    #pragma unroll
    for (int mi = 0; mi < 4; ++mi)
        #pragma unroll
        for (int ni = 0; ni < 2; ++ni)
            acc[mi][ni] = (f32x4){0.f, 0.f, 0.f, 0.f};

    #pragma unroll
    for (int kk = 0; kk < 4; ++kk) {
        const int kb = kk * 32 + kgrp;
        short8 af[4], bfv[2];
        #pragma unroll
        for (int mi = 0; mi < 4; ++mi)
            af[mi] = *(const short8*)&As[((mi * 16 + col) * 128 + kb) ^ fswz];
        #pragma unroll
        for (int ni = 0; ni < 2; ++ni)
            bfv[ni] = *(const short8*)&Bs[((wcol + ni * 16 + col) * 128 + kb) ^ fswz];
        #pragma unroll
        for (int mi = 0; mi < 4; ++mi)
            #pragma unroll
            for (int ni = 0; ni < 2; ++ni)
                acc[mi][ni] = __builtin_amdgcn_mfma_f32_16x16x32_bf16(
                    af[mi], bfv[ni], acc[mi][ni], 0, 0, 0);
    }

    const int orow = (lane >> 4) * 4;
    #pragma unroll
    for (int mi = 0; mi < 4; ++mi)
        #pragma unroll
        for (int ni = 0; ni < 2; ++ni)
            #pragma unroll
            for (int j = 0; j < 4; ++j)
                out[(size_t)(row0 + mi * 16 + orow + j) * 128 + wcol + ni * 16 + col] =
                    acc[mi][ni][j];
}

// ---------------------------------------------------------------------------
extern "C" void kernel_launch(void* const* d_in, const int* in_sizes, int n_in,
                              void* d_out, int out_size, void* d_ws, size_t ws_size,
                              hipStream_t stream)
{
    const float* query = (const float*)d_in[0];
    const float* key   = (const float*)d_in[1];
    const float* value = (const float*)d_in[2];
    const float* Wq    = (const float*)d_in[3];
    const float* bq    = (const float*)d_in[4];
    const float* Wk    = (const float*)d_in[5];
    const float* bk    = (const float*)d_in[6];
    const float* Wv    = (const float*)d_in[7];
    const float* bv    = (const float*)d_in[8];
    float* out = (float*)d_out;

    ushort* qp   = (ushort*)d_ws;                    // 16384*128 bf16
    ushort* kp   = qp + (size_t)MROWS * 128;
    ushort* vp   = kp + (size_t)MROWS * 128;
    ushort* Wt   = vp + (size_t)MROWS * 128;         // 3*128*1024 bf16
    ushort* part = Wt + (size_t)3 * 128 * 1024;      // 8*32*16384 bf16
    ushort* Mt   = part + (size_t)8 * 32 * 16384;    // 8*16384 bf16

    dim3 blk(256);
    prep_kernel<<<dim3(16, 2, 3), blk, 0, stream>>>(Wq, Wk, Wv, Wt);
    proj_kernel<<<dim3(256, 3), blk, 0, stream>>>(query, bq, key, bk, value, bv,
                                                  Wt, qp, kp, vp);
    ktv_kernel<<<dim3(32, NB), blk, 0, stream>>>(kp, vp, part);
    reduce_kernel<<<512, blk, 0, stream>>>(part, Mt);
    qm_kernel<<<MROWS / 64, blk, 0, stream>>>(qp, Mt, out);
}

// Round 8
// 87.468 us; speedup vs baseline: 1.3490x; 1.3490x over previous
//
#include <hip/hip_runtime.h>
#include <hip/hip_bf16.h>

typedef __attribute__((ext_vector_type(8))) short short8;
typedef __attribute__((ext_vector_type(4))) float f32x4;

#define NB 8
#define LQ 2048
#define LK 2048
#define DIN 1024
#define MROWS (NB * LQ)   // 16384

static constexpr float KSCALE = 0.022097086912079608f; // 1/sqrt(2048)

__device__ __forceinline__ ushort f2bf(float f) {
    union { float f; unsigned int u; } v; v.f = f;
    unsigned int r = v.u + 0x7FFFu + ((v.u >> 16) & 1u);   // RNE
    return (ushort)(r >> 16);
}
__device__ __forceinline__ float bf2f(ushort u) {
    union { unsigned int u; float f; } v; v.u = ((unsigned int)u) << 16;
    return v.f;
}

// async global->LDS, 16B per lane; LDS dst is wave-uniform base + lane*16
__device__ __forceinline__ void gl16(const void* g, void* l) {
    __builtin_amdgcn_global_load_lds(
        (const __attribute__((address_space(1))) void*)g,
        (__attribute__((address_space(3))) void*)l, 16, 0, 0);
}

// ---------------------------------------------------------------------------
// prep: Wt[p][n][k] = bf16(W_p[k][n])  (transpose+convert, LDS tiled)
// ---------------------------------------------------------------------------
__global__ __launch_bounds__(256) void prep_kernel(
    const float* __restrict__ Wq, const float* __restrict__ Wk,
    const float* __restrict__ Wv, ushort* __restrict__ Wt)
{
    const float* W = (blockIdx.z == 0) ? Wq : (blockIdx.z == 1) ? Wk : Wv;
    ushort* O = Wt + (size_t)blockIdx.z * 128 * 1024;
    const int k0 = blockIdx.x * 64, n0 = blockIdx.y * 64;
    __shared__ float tile[64][65];
    const int t = threadIdx.x;
    {
        const int r = t >> 4, c = (t & 15) * 4;
        #pragma unroll
        for (int i = 0; i < 4; ++i) {
            float4 v = *(const float4*)&W[(size_t)(k0 + r + i * 16) * 128 + n0 + c];
            tile[r + i * 16][c + 0] = v.x; tile[r + i * 16][c + 1] = v.y;
            tile[r + i * 16][c + 2] = v.z; tile[r + i * 16][c + 3] = v.w;
        }
    }
    __syncthreads();
    {
        const int n = t >> 2, kc = (t & 3) * 16;
        ushort tmp[16];
        #pragma unroll
        for (int j = 0; j < 16; ++j) tmp[j] = f2bf(tile[kc + j][n]);
        *(uint4*)&O[(size_t)(n0 + n) * 1024 + k0 + kc]     = *(uint4*)&tmp[0];
        *(uint4*)&O[(size_t)(n0 + n) * 1024 + k0 + kc + 8] = *(uint4*)&tmp[8];
    }
}

// ---------------------------------------------------------------------------
// gemm64: Ys(LDS, swizzled bf16 64x128) = relu(X[row0..+64][1024] @ W + b),
// optionally also written to Yg global. R6's proven ring loop, verbatim:
// T3+T4 3-deep LDS ring, BK=32, counted vmcnt(4), raw s_barrier.
// As = 3*2048 fp32 (24 KB), Bs = 3*4096 ushort (24 KB); Ys aliases As.
// ---------------------------------------------------------------------------
__device__ __forceinline__ void gemm64(
    const float* __restrict__ X, const ushort* __restrict__ W,
    const float* __restrict__ bias, ushort* __restrict__ Yg, const int doY,
    const int row0, const int tid, float* As, ushort* Bs)
{
    __syncthreads();   // prior phase's LDS reads done; ring safe to overwrite

    const int lane = tid & 63;
    const int w    = tid >> 6;
    const int wr   = (w >> 1) * 32;
    const int wc   = (w & 1) * 64;

    // staging source addresses (inverse-swizzled per lane) — see R6 notes
    const int rA = w * 16 + (lane >> 3);
    const int cA = (lane & 7) ^ (rA & 7);
    const float* gA0 = X + (size_t)(row0 + rA) * DIN + cA * 4;
    const float* gA1 = gA0 + (size_t)8 * DIN;
    const int sB = w * 16 + (lane >> 3);
    const int cB = (lane & 7) ^ (sB & 7);
    const int nB = 2 * sB + (cB >> 2);
    const ushort* gB0 = W + (size_t)nB * DIN + (cB & 3) * 8;
    const ushort* gB1 = gB0 + (size_t)16 * DIN;

    // fragment read offsets (swizzled)
    const int col = lane & 15;
    const int kg  = (lane >> 4) * 8;
    const int c0  = kg >> 2;
    const int bc  = kg >> 3;
    const int ra  = wr + col;
    const int axr = ra & 7;
    const int aLo = ra * 32 + ((c0 ^ axr) << 2);
    const int aHi = ra * 32 + (((c0 + 1) ^ axr) << 2);
    const int nb0 = wc + col;
    const int bO  = (nb0 >> 1) * 64 +
                    (((((nb0 & 1) << 2) | bc) ^ ((nb0 >> 1) & 7)) << 3);

    f32x4 acc[2][4];
    #pragma unroll
    for (int mi = 0; mi < 2; ++mi)
        #pragma unroll
        for (int ni = 0; ni < 4; ++ni)
            acc[mi][ni] = (f32x4){0.f, 0.f, 0.f, 0.f};

#define STAGE(s_, t_) do {                                                    \
    gl16(gA0 + (t_) * 32, &As[(s_) * 2048 + (w * 16) * 32]);                  \
    gl16(gA1 + (t_) * 32, &As[(s_) * 2048 + (w * 16 + 8) * 32]);              \
    gl16(gB0 + (t_) * 32, &Bs[(s_) * 4096 + (w * 16) * 64]);                  \
    gl16(gB1 + (t_) * 32, &Bs[(s_) * 4096 + (w * 16 + 8) * 64]);              \
} while (0)

#define STEP(s_) do {                                                         \
    float4 lo0 = *(const float4*)&As[(s_) * 2048 + aLo];                      \
    float4 hi0 = *(const float4*)&As[(s_) * 2048 + aHi];                      \
    float4 lo1 = *(const float4*)&As[(s_) * 2048 + aLo + 512];                \
    float4 hi1 = *(const float4*)&As[(s_) * 2048 + aHi + 512];                \
    short8 bf0 = *(const short8*)&Bs[(s_) * 4096 + bO];                       \
    short8 bf1 = *(const short8*)&Bs[(s_) * 4096 + bO + 512];                 \
    short8 bf2 = *(const short8*)&Bs[(s_) * 4096 + bO + 1024];                \
    short8 bf3 = *(const short8*)&Bs[(s_) * 4096 + bO + 1536];                \
    union { short8 s; unsigned u[4]; } a0_, a1_;                              \
    a0_.u[0] = (unsigned)f2bf(lo0.x) | ((unsigned)f2bf(lo0.y) << 16);         \
    a0_.u[1] = (unsigned)f2bf(lo0.z) | ((unsigned)f2bf(lo0.w) << 16);         \
    a0_.u[2] = (unsigned)f2bf(hi0.x) | ((unsigned)f2bf(hi0.y) << 16);         \
    a0_.u[3] = (unsigned)f2bf(hi0.z) | ((unsigned)f2bf(hi0.w) << 16);         \
    a1_.u[0] = (unsigned)f2bf(lo1.x) | ((unsigned)f2bf(lo1.y) << 16);         \
    a1_.u[1] = (unsigned)f2bf(lo1.z) | ((unsigned)f2bf(lo1.w) << 16);         \
    a1_.u[2] = (unsigned)f2bf(hi1.x) | ((unsigned)f2bf(hi1.y) << 16);         \
    a1_.u[3] = (unsigned)f2bf(hi1.z) | ((unsigned)f2bf(hi1.w) << 16);         \
    short8 af0 = a0_.s, af1 = a1_.s;                                          \
    acc[0][0] = __builtin_amdgcn_mfma_f32_16x16x32_bf16(af0, bf0, acc[0][0], 0, 0, 0); \
    acc[1][0] = __builtin_amdgcn_mfma_f32_16x16x32_bf16(af1, bf0, acc[1][0], 0, 0, 0); \
    acc[0][1] = __builtin_amdgcn_mfma_f32_16x16x32_bf16(af0, bf1, acc[0][1], 0, 0, 0); \
    acc[1][1] = __builtin_amdgcn_mfma_f32_16x16x32_bf16(af1, bf1, acc[1][1], 0, 0, 0); \
    acc[0][2] = __builtin_amdgcn_mfma_f32_16x16x32_bf16(af0, bf2, acc[0][2], 0, 0, 0); \
    acc[1][2] = __builtin_amdgcn_mfma_f32_16x16x32_bf16(af1, bf2, acc[1][2], 0, 0, 0); \
    acc[0][3] = __builtin_amdgcn_mfma_f32_16x16x32_bf16(af0, bf3, acc[0][3], 0, 0, 0); \
    acc[1][3] = __builtin_amdgcn_mfma_f32_16x16x32_bf16(af1, bf3, acc[1][3], 0, 0, 0); \
} while (0)

#define FENCE(n_) do {                                                        \
    asm volatile("s_waitcnt vmcnt(" #n_ ")" ::: "memory");                    \
    __builtin_amdgcn_sched_barrier(0);                                        \
    __builtin_amdgcn_s_barrier();                                             \
    __builtin_amdgcn_sched_barrier(0);                                        \
} while (0)

    STAGE(0, 0);
    STAGE(1, 1);
    FENCE(4);

    #pragma unroll 1
    for (int t = 0; t < 30; t += 3) {
        STAGE(2, t + 2); STEP(0); FENCE(4);
        STAGE(0, t + 3); STEP(1); FENCE(4);
        STAGE(1, t + 4); STEP(2); FENCE(4);
    }
    STEP(0);            // t=30
    FENCE(0);           // stage 31 complete
    STEP(1);            // t=31
    __syncthreads();    // all ring reads done; LDS free for Ys reuse

#undef STAGE
#undef STEP
#undef FENCE

    float bb[4];
    #pragma unroll
    for (int ni = 0; ni < 4; ++ni) bb[ni] = bias[wc + ni * 16 + col];

    ushort* Ys = (ushort*)As;           // 16 KB of the 24 KB A-ring
    const int orow4 = (lane >> 4) * 4;
    #pragma unroll
    for (int mi = 0; mi < 2; ++mi)
        #pragma unroll
        for (int ni = 0; ni < 4; ++ni)
            #pragma unroll
            for (int j = 0; j < 4; ++j) {
                float v = fmaxf(acc[mi][ni][j] + bb[ni], 0.f);
                const int rl = wr + mi * 16 + orow4 + j;
                const int cl = wc + ni * 16 + col;
                Ys[(rl * 128 + cl) ^ ((rl & 15) << 3)] = f2bf(v);
            }
    __syncthreads();

    if (doY) {
        const int r = tid >> 2, c = (tid & 3) * 32;
        const int swz = (r & 15) << 3;
        ushort* Ygr = Yg + (size_t)(row0 + r) * 128 + c;
        #pragma unroll
        for (int j = 0; j < 4; ++j)
            *(uint4*)&Ygr[j * 8] = *(const uint4*)&Ys[(r * 128 + c + j * 8) ^ swz];
    }
}

// ---------------------------------------------------------------------------
// fused proj: grid 512.
//   bid <  256: qp rows = relu(query @ Wq + bq)                  -> qp
//   bid >= 256: k-GEMM -> kp (global, L2-hot bounce);
//               v-GEMM -> v-tile stays in LDS (no vp write);
//               ktv:    part[chunk][v][e] = sum_r v[r][v]*k[r][e] -> part
// 48 KB LDS, 3 blocks/CU; all 512 blocks co-resident.
// ---------------------------------------------------------------------------
__global__ __launch_bounds__(256, 3) void proj_fused_kernel(
    const float* __restrict__ query, const float* __restrict__ bq,
    const float* __restrict__ key,   const float* __restrict__ bk,
    const float* __restrict__ value, const float* __restrict__ bv,
    const ushort* __restrict__ Wt,
    ushort* __restrict__ qp, ushort* __restrict__ kp,
    ushort* __restrict__ part)
{
    __shared__ __align__(16) float  As[3 * 2048];    // 24 KB
    __shared__ __align__(16) ushort Bs[3 * 4096];    // 24 KB

    const int tid = threadIdx.x;
    const int bid = blockIdx.x;

    if (bid < 256) {
        gemm64(query, Wt, bq, qp, 1, bid * 64, tid, As, Bs);
        return;
    }

    const int chunk = bid - 256;        // 0..255 == b*32 + local
    const int row0  = chunk * 64;

    // k projection -> kp global (this block reads it back from L2)
    gemm64(key,   Wt + 1 * 131072, bk, kp, 1, row0, tid, As, Bs);
    // v projection -> v-tile in Ys (aliases As); no global write
    gemm64(value, Wt + 2 * 131072, bv, (ushort*)0, 0, row0, tid, As, Bs);

    // ---- ktv phase: k from kp (L2) staged into Bs region; v from Ys ----
    ushort* Ysv = (ushort*)As;          // swizzled v-tile
    ushort* ksr = Bs;                   // 16 KB plain k rows
    {
        const ushort* Kg = kp + (size_t)row0 * 128;
        const int r = tid >> 2, cc = (tid & 3) * 32;
        #pragma unroll
        for (int j = 0; j < 4; ++j)
            *(uint4*)&ksr[r * 128 + cc + j * 8] = *(const uint4*)&Kg[r * 128 + cc + j * 8];
    }
    __syncthreads();

    const int e0 = (tid & 15) * 8;
    const int v0 = (tid >> 4) * 8;
    float acc2[8][8];
    #pragma unroll
    for (int i = 0; i < 8; ++i)
        #pragma unroll
        for (int j = 0; j < 8; ++j) acc2[i][j] = 0.f;

    for (int r = 0; r < 64; ++r) {
        uint4 kf = *(const uint4*)&ksr[r * 128 + e0];
        uint4 vf = *(const uint4*)&Ysv[(r * 128 + v0) ^ ((r & 15) << 3)];
        const ushort* kw = (const ushort*)&kf;
        const ushort* vw = (const ushort*)&vf;
        float ke[8], ve[8];
        #pragma unroll
        for (int j = 0; j < 8; ++j) { ke[j] = bf2f(kw[j]); ve[j] = bf2f(vw[j]); }
        #pragma unroll
        for (int i = 0; i < 8; ++i)
            #pragma unroll
            for (int j = 0; j < 8; ++j)
                acc2[i][j] = fmaf(ve[i], ke[j], acc2[i][j]);
    }

    ushort* P = part + (size_t)chunk * 16384;
    #pragma unroll
    for (int i = 0; i < 8; ++i) {
        ushort tmp[8];
        #pragma unroll
        for (int j = 0; j < 8; ++j) tmp[j] = f2bf(acc2[i][j]);
        *(uint4*)&P[(v0 + i) * 128 + e0] = *(uint4*)&tmp[0];
    }
}

// ---------------------------------------------------------------------------
// reduce: Mt[b][v*128+e] = bf16(KSCALE * sum_{c<32} part[b][c][v*128+e])
// ---------------------------------------------------------------------------
__global__ __launch_bounds__(256) void reduce_kernel(
    const ushort* __restrict__ part, ushort* __restrict__ Mt)
{
    const int g = blockIdx.x * 256 + threadIdx.x;
    const int b = g >> 14, idx = g & 16383;
    const ushort* P = part + (size_t)b * 32 * 16384 + idx;
    float s = 0.f;
    #pragma unroll
    for (int c = 0; c < 32; ++c) s += bf2f(P[(size_t)c * 16384]);
    Mt[g] = f2bf(s * KSCALE);
}

// ---------------------------------------------------------------------------
// qm: out[row][v] = sum_e qp[row][e] * Mt[b][v][e]
// ---------------------------------------------------------------------------
__global__ __launch_bounds__(256) void qm_kernel(
    const ushort* __restrict__ qp, const ushort* __restrict__ Mt,
    float* __restrict__ out)
{
    const int row0 = blockIdx.x * 64;
    const int b = row0 >> 11;
    const ushort* Q = qp + (size_t)row0 * 128;
    const ushort* M = Mt + (size_t)b * 16384;

    __shared__ __align__(16) ushort As[64 * 128];
    __shared__ __align__(16) ushort Bs[128 * 128];

    const int t = threadIdx.x;
    {
        const int r = t >> 2, cc = (t & 3) * 32;
        const int swz = (r & 15) << 3;
        #pragma unroll
        for (int j = 0; j < 4; ++j)
            *(uint4*)&As[(r * 128 + cc + j * 8) ^ swz] = *(const uint4*)&Q[r * 128 + cc + j * 8];
    }
    {
        const int r = t >> 1, cc = (t & 1) * 64;
        const int swz = (r & 15) << 3;
        #pragma unroll
        for (int j = 0; j < 8; ++j)
            *(uint4*)&Bs[(r * 128 + cc + j * 8) ^ swz] = *(const uint4*)&M[r * 128 + cc + j * 8];
    }
    __syncthreads();

    const int lane = t & 63;
    const int wcol = (t >> 6) * 32;
    const int col  = lane & 15;
    const int kgrp = (lane >> 4) * 8;
    const int fswz = col << 3;

    f32x4 acc[4][2];
    #pragma unroll
    for (int mi = 0; mi < 4; ++mi)
        #pragma unroll
        for (int ni = 0; ni < 2; ++ni)
            acc[mi][ni] = (f32x4){0.f, 0.f, 0.f, 0.f};

    #pragma unroll
    for (int kk = 0; kk < 4; ++kk) {
        const int kb = kk * 32 + kgrp;
        short8 af[4], bfv[2];
        #pragma unroll
        for (int mi = 0; mi < 4; ++mi)
            af[mi] = *(const short8*)&As[((mi * 16 + col) * 128 + kb) ^ fswz];
        #pragma unroll
        for (int ni = 0; ni < 2; ++ni)
            bfv[ni] = *(const short8*)&Bs[((wcol + ni * 16 + col) * 128 + kb) ^ fswz];
        #pragma unroll
        for (int mi = 0; mi < 4; ++mi)
            #pragma unroll
            for (int ni = 0; ni < 2; ++ni)
                acc[mi][ni] = __builtin_amdgcn_mfma_f32_16x16x32_bf16(
                    af[mi], bfv[ni], acc[mi][ni], 0, 0, 0);
    }

    const int orow = (lane >> 4) * 4;
    #pragma unroll
    for (int mi = 0; mi < 4; ++mi)
        #pragma unroll
        for (int ni = 0; ni < 2; ++ni)
            #pragma unroll
            for (int j = 0; j < 4; ++j)
                out[(size_t)(row0 + mi * 16 + orow + j) * 128 + wcol + ni * 16 + col] =
                    acc[mi][ni][j];
}

// ---------------------------------------------------------------------------
extern "C" void kernel_launch(void* const* d_in, const int* in_sizes, int n_in,
                              void* d_out, int out_size, void* d_ws, size_t ws_size,
                              hipStream_t stream)
{
    const float* query = (const float*)d_in[0];
    const float* key   = (const float*)d_in[1];
    const float* value = (const float*)d_in[2];
    const float* Wq    = (const float*)d_in[3];
    const float* bq    = (const float*)d_in[4];
    const float* Wk    = (const float*)d_in[5];
    const float* bk    = (const float*)d_in[6];
    const float* Wv    = (const float*)d_in[7];
    const float* bv    = (const float*)d_in[8];
    float* out = (float*)d_out;

    ushort* qp   = (ushort*)d_ws;                    // 16384*128 bf16
    ushort* kp   = qp + (size_t)MROWS * 128;
    ushort* vp   = kp + (size_t)MROWS * 128;         // unused (kept for layout)
    ushort* Wt   = vp + (size_t)MROWS * 128;         // 3*128*1024 bf16
    ushort* part = Wt + (size_t)3 * 128 * 1024;      // 8*32*16384 bf16
    ushort* Mt   = part + (size_t)8 * 32 * 16384;    // 8*16384 bf16

    dim3 blk(256);
    prep_kernel<<<dim3(16, 2, 3), blk, 0, stream>>>(Wq, Wk, Wv, Wt);
    proj_fused_kernel<<<512, blk, 0, stream>>>(query, bq, key, bk, value, bv,
                                               Wt, qp, kp, part);
    reduce_kernel<<<512, blk, 0, stream>>>(part, Mt);
    qm_kernel<<<MROWS / 64, blk, 0, stream>>>(qp, Mt, out);
}

// Round 9
// 77.602 us; speedup vs baseline: 1.5205x; 1.1271x over previous
//
#include <hip/hip_runtime.h>
#include <hip/hip_bf16.h>

typedef __attribute__((ext_vector_type(8))) short short8;
typedef __attribute__((ext_vector_type(4))) float f32x4;

#define NB 8
#define LQ 2048
#define LK 2048
#define DIN 1024
#define MROWS (NB * LQ)   // 16384

static constexpr float KSCALE = 0.022097086912079608f; // 1/sqrt(2048)

__device__ __forceinline__ ushort f2bf(float f) {
    union { float f; unsigned int u; } v; v.f = f;
    unsigned int r = v.u + 0x7FFFu + ((v.u >> 16) & 1u);   // RNE
    return (ushort)(r >> 16);
}
__device__ __forceinline__ float bf2f(ushort u) {
    union { unsigned int u; float f; } v; v.u = ((unsigned int)u) << 16;
    return v.f;
}
__device__ __forceinline__ unsigned pk2(float lo, float hi) {
    __hip_bfloat162 h = __float22bfloat162_rn(float2{lo, hi});   // v_cvt_pk_bf16_f32
    union { __hip_bfloat162 h; unsigned u; } c; c.h = h; return c.u;
}
__device__ __forceinline__ short8 cvt8(float4 lo, float4 hi) {
    union { short8 s; unsigned u[4]; } r;
    r.u[0] = pk2(lo.x, lo.y);
    r.u[1] = pk2(lo.z, lo.w);
    r.u[2] = pk2(hi.x, hi.y);
    r.u[3] = pk2(hi.z, hi.w);
    return r.s;
}

// async global->LDS, 16B per lane; LDS dst is wave-uniform base + lane*16
__device__ __forceinline__ void gl16(const void* g, void* l) {
    __builtin_amdgcn_global_load_lds(
        (const __attribute__((address_space(1))) void*)g,
        (__attribute__((address_space(3))) void*)l, 16, 0, 0);
}

// ---------------------------------------------------------------------------
// prep: Wt[p][n][k] = bf16(W_p[k][n])  (transpose+convert, LDS tiled)
// ---------------------------------------------------------------------------
__global__ __launch_bounds__(256) void prep_kernel(
    const float* __restrict__ Wq, const float* __restrict__ Wk,
    const float* __restrict__ Wv, ushort* __restrict__ Wt)
{
    const float* W = (blockIdx.z == 0) ? Wq : (blockIdx.z == 1) ? Wk : Wv;
    ushort* O = Wt + (size_t)blockIdx.z * 128 * 1024;
    const int k0 = blockIdx.x * 64, n0 = blockIdx.y * 64;
    __shared__ float tile[64][65];
    const int t = threadIdx.x;
    {
        const int r = t >> 4, c = (t & 15) * 4;
        #pragma unroll
        for (int i = 0; i < 4; ++i) {
            float4 v = *(const float4*)&W[(size_t)(k0 + r + i * 16) * 128 + n0 + c];
            tile[r + i * 16][c + 0] = v.x; tile[r + i * 16][c + 1] = v.y;
            tile[r + i * 16][c + 2] = v.z; tile[r + i * 16][c + 3] = v.w;
        }
    }
    __syncthreads();
    {
        const int n = t >> 2, kc = (t & 3) * 16;
        ushort tmp[16];
        #pragma unroll
        for (int j = 0; j < 16; ++j) tmp[j] = f2bf(tile[kc + j][n]);
        *(uint4*)&O[(size_t)(n0 + n) * 1024 + k0 + kc]     = *(uint4*)&tmp[0];
        *(uint4*)&O[(size_t)(n0 + n) * 1024 + k0 + kc + 8] = *(uint4*)&tmp[8];
    }
}

// ---------------------------------------------------------------------------
// proj: Y = bf16(relu(X[16384,1024] @ W + b))
// PER-WAVE streaming, ZERO barriers: one 64-thread block = one wave owning a
// 32x64 output tile with a PRIVATE 4-slot LDS ring (A 32x32 fp32 + B 64x32
// bf16 per slot = 8 KB; 32 KB total -> 5 waves/CU). Staging via
// global_load_lds (side-effecting intrinsic: hipcc can't sink it, unlike
// R5/R7's register prefetch), 3 stages in flight, per-wave counted
// s_waitcnt vmcnt(16) -> ~2 steps of latency cover, no lockstep.
// Swizzle formulas identical to R6 (row&7 involution survives 64->32 rows).
// Col-half pairing via bid bit3 so X-slab sharers land on the same XCD.
// ---------------------------------------------------------------------------
__global__ __launch_bounds__(64) void proj_kernel(
    const float* __restrict__ Xq, const float* __restrict__ bq,
    const float* __restrict__ Xk, const float* __restrict__ bk,
    const float* __restrict__ Xv, const float* __restrict__ bv,
    const ushort* __restrict__ Wt,
    ushort* __restrict__ qp, ushort* __restrict__ kp, ushort* __restrict__ vp)
{
    const int p = blockIdx.y;
    const float* X; const float* bias; ushort* Y;
    if (p == 0)      { X = Xq; bias = bq; Y = qp; }
    else if (p == 1) { X = Xk; bias = bk; Y = kp; }
    else             { X = Xv; bias = bv; Y = vp; }
    const ushort* W = Wt + (size_t)p * 131072;

    // XCD pairing: blocks x and x+8 share the X slab and (bid%8 heuristic)
    // the same XCD's L2. Bijective: x = (g<<4)|(h<<3)|s -> rt = g*8+s.
    const int x    = blockIdx.x;
    const int rt   = ((x >> 4) << 3) | (x & 7);     // 0..511
    const int half = (x >> 3) & 1;
    const int row0 = rt * 32;
    const int wc   = half * 64;

    __shared__ __align__(16) float  As[4 * 1024];   // 16 KB: 4 slots of 32x32 fp32
    __shared__ __align__(16) ushort Bs[4 * 2048];   // 16 KB: 4 slots of 64x32 bf16

    const int lane = threadIdx.x;   // 0..63, single wave
    const int l3 = lane >> 3, l7 = lane & 7;

    // staging sources (inverse-swizzled per lane; chunk ^= row&7, row&7 == l3)
    const int cA = l7 ^ l3;
    const float* gA = X + (size_t)(row0 + l3) * DIN + cA * 4;       // +8j rows/call
    const int cB = l7 ^ l3;
    const int nB = 2 * l3 + (cB >> 2);
    const ushort* gB = W + (size_t)(wc + nB) * DIN + (cB & 3) * 8;  // +16j rows/call

    // fragment read offsets (swizzled; same family as R6)
    const int col = lane & 15;
    const int kg  = (lane >> 4) * 8;
    const int c0  = kg >> 2;
    const int bc  = kg >> 3;
    const int axr = col & 7;
    const int aLo = col * 32 + ((c0 ^ axr) << 2);
    const int aHi = col * 32 + (((c0 + 1) ^ axr) << 2);
    const int bO  = (col >> 1) * 64 +
                    (((((col & 1) << 2) | bc) ^ ((col >> 1) & 7)) << 3);

    f32x4 acc[2][4];
    #pragma unroll
    for (int mi = 0; mi < 2; ++mi)
        #pragma unroll
        for (int ni = 0; ni < 4; ++ni)
            acc[mi][ni] = (f32x4){0.f, 0.f, 0.f, 0.f};

#define STAGE(s_, t_) do {                                                    \
    gl16(gA + (t_) * 32,            &As[(s_) * 1024 + 0 * 256]);              \
    gl16(gA + (t_) * 32 +  8 * DIN, &As[(s_) * 1024 + 1 * 256]);              \
    gl16(gA + (t_) * 32 + 16 * DIN, &As[(s_) * 1024 + 2 * 256]);              \
    gl16(gA + (t_) * 32 + 24 * DIN, &As[(s_) * 1024 + 3 * 256]);              \
    gl16(gB + (t_) * 32,            &Bs[(s_) * 2048 + 0 * 512]);              \
    gl16(gB + (t_) * 32 + 16 * DIN, &Bs[(s_) * 2048 + 1 * 512]);              \
    gl16(gB + (t_) * 32 + 32 * DIN, &Bs[(s_) * 2048 + 2 * 512]);              \
    gl16(gB + (t_) * 32 + 48 * DIN, &Bs[(s_) * 2048 + 3 * 512]);              \
} while (0)

#define STEP(s_) do {                                                         \
    float4 lo0 = *(const float4*)&As[(s_) * 1024 + aLo];                      \
    float4 hi0 = *(const float4*)&As[(s_) * 1024 + aHi];                      \
    float4 lo1 = *(const float4*)&As[(s_) * 1024 + aLo + 512];                \
    float4 hi1 = *(const float4*)&As[(s_) * 1024 + aHi + 512];                \
    short8 bf0 = *(const short8*)&Bs[(s_) * 2048 + bO];                       \
    short8 bf1 = *(const short8*)&Bs[(s_) * 2048 + bO + 512];                 \
    short8 bf2 = *(const short8*)&Bs[(s_) * 2048 + bO + 1024];                \
    short8 bf3 = *(const short8*)&Bs[(s_) * 2048 + bO + 1536];                \
    short8 af0 = cvt8(lo0, hi0);                                              \
    short8 af1 = cvt8(lo1, hi1);                                              \
    acc[0][0] = __builtin_amdgcn_mfma_f32_16x16x32_bf16(af0, bf0, acc[0][0], 0, 0, 0); \
    acc[1][0] = __builtin_amdgcn_mfma_f32_16x16x32_bf16(af1, bf0, acc[1][0], 0, 0, 0); \
    acc[0][1] = __builtin_amdgcn_mfma_f32_16x16x32_bf16(af0, bf1, acc[0][1], 0, 0, 0); \
    acc[1][1] = __builtin_amdgcn_mfma_f32_16x16x32_bf16(af1, bf1, acc[1][1], 0, 0, 0); \
    acc[0][2] = __builtin_amdgcn_mfma_f32_16x16x32_bf16(af0, bf2, acc[0][2], 0, 0, 0); \
    acc[1][2] = __builtin_amdgcn_mfma_f32_16x16x32_bf16(af1, bf2, acc[1][2], 0, 0, 0); \
    acc[0][3] = __builtin_amdgcn_mfma_f32_16x16x32_bf16(af0, bf3, acc[0][3], 0, 0, 0); \
    acc[1][3] = __builtin_amdgcn_mfma_f32_16x16x32_bf16(af1, bf3, acc[1][3], 0, 0, 0); \
} while (0)

#define FENCEW(n_) do {                                                       \
    asm volatile("s_waitcnt vmcnt(" #n_ ")" ::: "memory");                    \
    __builtin_amdgcn_sched_barrier(0);                                        \
} while (0)

    // prologue: 3 stages in flight (24 outstanding loads)
    STAGE(0, 0);
    STAGE(1, 1);
    STAGE(2, 2);

    #pragma unroll 1
    for (int t = 0; t < 28; t += 4) {
        FENCEW(16); STEP(0); STAGE(3, t + 3);
        FENCEW(16); STEP(1); STAGE(0, t + 4);
        FENCEW(16); STEP(2); STAGE(1, t + 5);
        FENCEW(16); STEP(3); STAGE(2, t + 6);
    }
    // peeled tail: k = 28..31
    FENCEW(16); STEP(0); STAGE(3, 31);
    FENCEW(16); STEP(1);
    FENCEW(8);  STEP(2);
    FENCEW(0);  STEP(3);

#undef STAGE
#undef STEP
#undef FENCEW

    float bb[4];
    #pragma unroll
    for (int ni = 0; ni < 4; ++ni) bb[ni] = bias[wc + ni * 16 + col];

    // epilogue: swizzled LDS bounce (slot 0 of As, disjoint from slot-3 reads)
    ushort* Ys = (ushort*)As;           // 32x64 bf16 = 4 KB
    const int orow4 = (lane >> 4) * 4;
    #pragma unroll
    for (int mi = 0; mi < 2; ++mi)
        #pragma unroll
        for (int ni = 0; ni < 4; ++ni)
            #pragma unroll
            for (int j = 0; j < 4; ++j) {
                float v = fmaxf(acc[mi][ni][j] + bb[ni], 0.f);
                const int rl = mi * 16 + orow4 + j;
                const int cl = ni * 16 + col;
                Ys[rl * 64 + (((cl >> 3) ^ (rl & 7)) << 3) + (cl & 7)] = f2bf(v);
            }
    asm volatile("s_waitcnt lgkmcnt(0)" ::: "memory");
    __builtin_amdgcn_sched_barrier(0);

    #pragma unroll
    for (int j2 = 0; j2 < 4; ++j2) {
        const int r  = j2 * 8 + l3;
        const int ch = l7;
        uint4 u = *(const uint4*)&Ys[r * 64 + ((ch ^ (r & 7)) << 3)];
        *(uint4*)&Y[(size_t)(row0 + r) * 128 + wc + ch * 8] = u;
    }
}

// ---------------------------------------------------------------------------
// ktv: per (batch, 64-row chunk): partial Mt_part[v][e] = sum_r v[r][v]*k[r][e]
// ---------------------------------------------------------------------------
__global__ __launch_bounds__(256) void ktv_kernel(
    const ushort* __restrict__ kp, const ushort* __restrict__ vp,
    ushort* __restrict__ part)
{
    const int b = blockIdx.y, chunk = blockIdx.x;
    const ushort* K = kp + ((size_t)b * LK + chunk * 64) * 128;
    const ushort* V = vp + ((size_t)b * LK + chunk * 64) * 128;
    ushort* P = part + ((size_t)(b * 32 + chunk)) * 16384;

    __shared__ __align__(16) ushort ks[64 * 128];
    __shared__ __align__(16) ushort vs[64 * 128];
    const int t = threadIdx.x;
    {
        const int r = t >> 2, cc = (t & 3) * 32;
        #pragma unroll
        for (int j = 0; j < 4; ++j) {
            *(uint4*)&ks[r * 128 + cc + j * 8] = *(const uint4*)&K[r * 128 + cc + j * 8];
            *(uint4*)&vs[r * 128 + cc + j * 8] = *(const uint4*)&V[r * 128 + cc + j * 8];
        }
    }
    __syncthreads();

    const int e0 = (t & 15) * 8;
    const int v0 = (t >> 4) * 8;
    float acc[8][8];
    #pragma unroll
    for (int i = 0; i < 8; ++i)
        #pragma unroll
        for (int j = 0; j < 8; ++j) acc[i][j] = 0.f;

    for (int r = 0; r < 64; ++r) {
        uint4 kf = *(const uint4*)&ks[r * 128 + e0];
        uint4 vf = *(const uint4*)&vs[r * 128 + v0];
        const ushort* kw = (const ushort*)&kf;
        const ushort* vw = (const ushort*)&vf;
        float ke[8], ve[8];
        #pragma unroll
        for (int j = 0; j < 8; ++j) { ke[j] = bf2f(kw[j]); ve[j] = bf2f(vw[j]); }
        #pragma unroll
        for (int i = 0; i < 8; ++i)
            #pragma unroll
            for (int j = 0; j < 8; ++j)
                acc[i][j] = fmaf(ve[i], ke[j], acc[i][j]);
    }

    #pragma unroll
    for (int i = 0; i < 8; ++i) {
        ushort tmp[8];
        #pragma unroll
        for (int j = 0; j < 8; ++j) tmp[j] = f2bf(acc[i][j]);
        *(uint4*)&P[(v0 + i) * 128 + e0] = *(uint4*)&tmp[0];
    }
}

// ---------------------------------------------------------------------------
// reduce: Mt[b][v*128+e] = bf16(KSCALE * sum_{c<32} part[b][c][v*128+e])
// ---------------------------------------------------------------------------
__global__ __launch_bounds__(256) void reduce_kernel(
    const ushort* __restrict__ part, ushort* __restrict__ Mt)
{
    const int g = blockIdx.x * 256 + threadIdx.x;
    const int b = g >> 14, idx = g & 16383;
    const ushort* P = part + (size_t)b * 32 * 16384 + idx;
    float s = 0.f;
    #pragma unroll
    for (int c = 0; c < 32; ++c) s += bf2f(P[(size_t)c * 16384]);
    Mt[g] = f2bf(s * KSCALE);
}

// ---------------------------------------------------------------------------
// qm: out[row][v] = sum_e qp[row][e] * Mt[b][v][e]
// ---------------------------------------------------------------------------
__global__ __launch_bounds__(256) void qm_kernel(
    const ushort* __restrict__ qp, const ushort* __restrict__ Mt,
    float* __restrict__ out)
{
    const int row0 = blockIdx.x * 64;
    const int b = row0 >> 11;
    const ushort* Q = qp + (size_t)row0 * 128;
    const ushort* M = Mt + (size_t)b * 16384;

    __shared__ __align__(16) ushort As[64 * 128];
    __shared__ __align__(16) ushort Bs[128 * 128];

    const int t = threadIdx.x;
    {
        const int r = t >> 2, cc = (t & 3) * 32;
        const int swz = (r & 15) << 3;
        #pragma unroll
        for (int j = 0; j < 4; ++j)
            *(uint4*)&As[(r * 128 + cc + j * 8) ^ swz] = *(const uint4*)&Q[r * 128 + cc + j * 8];
    }
    {
        const int r = t >> 1, cc = (t & 1) * 64;
        const int swz = (r & 15) << 3;
        #pragma unroll
        for (int j = 0; j < 8; ++j)
            *(uint4*)&Bs[(r * 128 + cc + j * 8) ^ swz] = *(const uint4*)&M[r * 128 + cc + j * 8];
    }
    __syncthreads();

    const int lane = t & 63;
    const int wcol = (t >> 6) * 32;
    const int col  = lane & 15;
    const int kgrp = (lane >> 4) * 8;
    const int fswz = col << 3;

    f32x4 acc[4][2];
    #pragma unroll
    for (int mi = 0; mi < 4; ++mi)
        #pragma unroll
        for (int ni = 0; ni < 2; ++ni)
            acc[mi][ni] = (f32x4){0.f, 0.f, 0.f, 0.f};

    #pragma unroll
    for (int kk = 0; kk < 4; ++kk) {
        const int kb = kk * 32 + kgrp;
        short8 af[4], bfv[2];
        #pragma unroll
        for (int mi = 0; mi < 4; ++mi)
            af[mi] = *(const short8*)&As[((mi * 16 + col) * 128 + kb) ^ fswz];
        #pragma unroll
        for (int ni = 0; ni < 2; ++ni)
            bfv[ni] = *(const short8*)&Bs[((wcol + ni * 16 + col) * 128 + kb) ^ fswz];
        #pragma unroll
        for (int mi = 0; mi < 4; ++mi)
            #pragma unroll
            for (int ni = 0; ni < 2; ++ni)
                acc[mi][ni] = __builtin_amdgcn_mfma_f32_16x16x32_bf16(
                    af[mi], bfv[ni], acc[mi][ni], 0, 0, 0);
    }

    const int orow = (lane >> 4) * 4;
    #pragma unroll
    for (int mi = 0; mi < 4; ++mi)
        #pragma unroll
        for (int ni = 0; ni < 2; ++ni)
            #pragma unroll
            for (int j = 0; j < 4; ++j)
                out[(size_t)(row0 + mi * 16 + orow + j) * 128 + wcol + ni * 16 + col] =
                    acc[mi][ni][j];
}

// ---------------------------------------------------------------------------
extern "C" void kernel_launch(void* const* d_in, const int* in_sizes, int n_in,
                              void* d_out, int out_size, void* d_ws, size_t ws_size,
                              hipStream_t stream)
{
    const float* query = (const float*)d_in[0];
    const float* key   = (const float*)d_in[1];
    const float* value = (const float*)d_in[2];
    const float* Wq    = (const float*)d_in[3];
    const float* bq    = (const float*)d_in[4];
    const float* Wk    = (const float*)d_in[5];
    const float* bk    = (const float*)d_in[6];
    const float* Wv    = (const float*)d_in[7];
    const float* bv    = (const float*)d_in[8];
    float* out = (float*)d_out;

    ushort* qp   = (ushort*)d_ws;                    // 16384*128 bf16
    ushort* kp   = qp + (size_t)MROWS * 128;
    ushort* vp   = kp + (size_t)MROWS * 128;
    ushort* Wt   = vp + (size_t)MROWS * 128;         // 3*128*1024 bf16
    ushort* part = Wt + (size_t)3 * 128 * 1024;      // 8*32*16384 bf16
    ushort* Mt   = part + (size_t)8 * 32 * 16384;    // 8*16384 bf16

    prep_kernel<<<dim3(16, 2, 3), 256, 0, stream>>>(Wq, Wk, Wv, Wt);
    proj_kernel<<<dim3(1024, 3), 64, 0, stream>>>(query, bq, key, bk, value, bv,
                                                  Wt, qp, kp, vp);
    ktv_kernel<<<dim3(32, NB), 256, 0, stream>>>(kp, vp, part);
    reduce_kernel<<<512, 256, 0, stream>>>(part, Mt);
    qm_kernel<<<MROWS / 64, 256, 0, stream>>>(qp, Mt, out);
}

// Round 10
// 61.735 us; speedup vs baseline: 1.9113x; 1.2570x over previous
//
#include <hip/hip_runtime.h>
#include <hip/hip_bf16.h>

typedef __attribute__((ext_vector_type(8))) short short8;
typedef __attribute__((ext_vector_type(4))) float f32x4;

#define NB 8
#define LQ 2048
#define LK 2048
#define DIN 1024
#define MROWS (NB * LQ)   // 16384

static constexpr float KSCALE = 0.022097086912079608f; // 1/sqrt(2048)

__device__ __forceinline__ ushort f2bf(float f) {
    union { float f; unsigned int u; } v; v.f = f;
    unsigned int r = v.u + 0x7FFFu + ((v.u >> 16) & 1u);   // RNE
    return (ushort)(r >> 16);
}
__device__ __forceinline__ float bf2f(ushort u) {
    union { unsigned int u; float f; } v; v.u = ((unsigned int)u) << 16;
    return v.f;
}
__device__ __forceinline__ unsigned pk2(float lo, float hi) {
    __hip_bfloat162 h = __float22bfloat162_rn(float2{lo, hi});   // v_cvt_pk_bf16_f32
    union { __hip_bfloat162 h; unsigned u; } c; c.h = h; return c.u;
}
__device__ __forceinline__ short8 cvt8(float4 lo, float4 hi) {
    union { short8 s; unsigned u[4]; } r;
    r.u[0] = pk2(lo.x, lo.y);
    r.u[1] = pk2(lo.z, lo.w);
    r.u[2] = pk2(hi.x, hi.y);
    r.u[3] = pk2(hi.z, hi.w);
    return r.s;
}

// async global->LDS, 16B per lane; LDS dst is wave-uniform base + lane*16
__device__ __forceinline__ void gl16(const void* g, void* l) {
    __builtin_amdgcn_global_load_lds(
        (const __attribute__((address_space(1))) void*)g,
        (__attribute__((address_space(3))) void*)l, 16, 0, 0);
}

// ---------------------------------------------------------------------------
// prep: Wt[p][n][k] = bf16(W_p[k][n])  (transpose+convert, LDS tiled)
// ---------------------------------------------------------------------------
__global__ __launch_bounds__(256) void prep_kernel(
    const float* __restrict__ Wq, const float* __restrict__ Wk,
    const float* __restrict__ Wv, ushort* __restrict__ Wt)
{
    const float* W = (blockIdx.z == 0) ? Wq : (blockIdx.z == 1) ? Wk : Wv;
    ushort* O = Wt + (size_t)blockIdx.z * 128 * 1024;
    const int k0 = blockIdx.x * 64, n0 = blockIdx.y * 64;
    __shared__ float tile[64][65];
    const int t = threadIdx.x;
    {
        const int r = t >> 4, c = (t & 15) * 4;
        #pragma unroll
        for (int i = 0; i < 4; ++i) {
            float4 v = *(const float4*)&W[(size_t)(k0 + r + i * 16) * 128 + n0 + c];
            tile[r + i * 16][c + 0] = v.x; tile[r + i * 16][c + 1] = v.y;
            tile[r + i * 16][c + 2] = v.z; tile[r + i * 16][c + 3] = v.w;
        }
    }
    __syncthreads();
    {
        const int n = t >> 2, kc = (t & 3) * 16;
        ushort tmp[16];
        #pragma unroll
        for (int j = 0; j < 16; ++j) tmp[j] = f2bf(tile[kc + j][n]);
        *(uint4*)&O[(size_t)(n0 + n) * 1024 + k0 + kc]     = *(uint4*)&tmp[0];
        *(uint4*)&O[(size_t)(n0 + n) * 1024 + k0 + kc + 8] = *(uint4*)&tmp[8];
    }
}

// ---------------------------------------------------------------------------
// proj: Y = bf16(relu(X[16384,1024] @ W + b))
// R6's proven T3+T4 ring (3-deep, BK=32, counted vmcnt, raw s_barrier),
// re-partitioned over 8 WAVES (512 threads) on the same 64x128 tile:
// LDS unchanged (48 KB -> 3 blocks/CU) but waves/CU doubles to 24 (6/SIMD)
// for latency hiding (R8 lesson: TLP, not prefetch depth, is the binding
// constraint — replay runs entirely from L3 with ~zero HBM fetch).
// Per wave: 16x64 sub-tile, 1 A-frag + 4 B-frags + 4 MFMA per step;
// staging = exactly 2 gl16/thread/stage; FENCE counts 4 -> vmcnt(2).
// All swizzle formulas identical to R6 (wave bases are multiples of 8).
// ---------------------------------------------------------------------------
__global__ __launch_bounds__(512, 6) void proj_kernel(
    const float* __restrict__ Xq, const float* __restrict__ bq,
    const float* __restrict__ Xk, const float* __restrict__ bk,
    const float* __restrict__ Xv, const float* __restrict__ bv,
    const ushort* __restrict__ Wt,
    ushort* __restrict__ qp, ushort* __restrict__ kp, ushort* __restrict__ vp)
{
    const int p = blockIdx.y;
    const float* X; const float* bias; ushort* Y;
    if (p == 0)      { X = Xq; bias = bq; Y = qp; }
    else if (p == 1) { X = Xk; bias = bk; Y = kp; }
    else             { X = Xv; bias = bv; Y = vp; }
    const ushort* W = Wt + (size_t)p * 131072;

    __shared__ __align__(16) float  As[3 * 2048];    // 24 KB: 3 slots 64x32 fp32
    __shared__ __align__(16) ushort Bs[3 * 4096];    // 24 KB: 3 slots 128x32 bf16

    const int tid  = threadIdx.x;
    const int lane = tid & 63;
    const int w    = tid >> 6;          // 0..7
    const int wr   = (w >> 1) * 16;     // wave row base: 0,16,32,48
    const int wc   = (w & 1) * 64;      // wave col base: 0,64
    const int row0 = blockIdx.x * 64;

    // ---- staging sources (inverse-swizzled per lane; R6 formula family) ----
    // A: wave w stages rows [w*8, w*8+8); lane l -> row w*8+(l>>3), phys chunk l&7
    const int rA = w * 8 + (lane >> 3);
    const int cA = (lane & 7) ^ (lane >> 3);            // (rA&7) == (l>>3)
    const float* gA = X + (size_t)(row0 + rA) * DIN + cA * 4;
    // B: wave w stages superrows [w*8, w*8+8) (superrow = 2 n-rows x 32 bf16)
    const int sB = w * 8 + (lane >> 3);
    const int cB = (lane & 7) ^ (lane >> 3);
    const int nB = 2 * sB + (cB >> 2);
    const ushort* gB = W + (size_t)nB * DIN + (cB & 3) * 8;

    // ---- fragment read offsets (swizzled; R6 family) ----
    const int col = lane & 15;
    const int kg  = (lane >> 4) * 8;
    const int c0  = kg >> 2;
    const int bc  = kg >> 3;
    const int ra  = wr + col;
    const int axr = ra & 7;
    const int aLo = ra * 32 + ((c0 ^ axr) << 2);
    const int aHi = ra * 32 + (((c0 + 1) ^ axr) << 2);
    const int nb0 = wc + col;
    const int bO  = (nb0 >> 1) * 64 +
                    (((((nb0 & 1) << 2) | bc) ^ ((nb0 >> 1) & 7)) << 3);

    f32x4 acc[4];
    #pragma unroll
    for (int ni = 0; ni < 4; ++ni) acc[ni] = (f32x4){0.f, 0.f, 0.f, 0.f};

#define STAGE(s_, t_) do {                                                    \
    gl16(gA + (t_) * 32, &As[(s_) * 2048 + w * 256]);                         \
    gl16(gB + (t_) * 32, &Bs[(s_) * 4096 + w * 512]);                         \
} while (0)

#define STEP(s_) do {                                                         \
    float4 lo = *(const float4*)&As[(s_) * 2048 + aLo];                       \
    float4 hi = *(const float4*)&As[(s_) * 2048 + aHi];                       \
    short8 bf0 = *(const short8*)&Bs[(s_) * 4096 + bO];                       \
    short8 bf1 = *(const short8*)&Bs[(s_) * 4096 + bO + 512];                 \
    short8 bf2 = *(const short8*)&Bs[(s_) * 4096 + bO + 1024];                \
    short8 bf3 = *(const short8*)&Bs[(s_) * 4096 + bO + 1536];                \
    short8 af0 = cvt8(lo, hi);                                                \
    acc[0] = __builtin_amdgcn_mfma_f32_16x16x32_bf16(af0, bf0, acc[0], 0, 0, 0); \
    acc[1] = __builtin_amdgcn_mfma_f32_16x16x32_bf16(af0, bf1, acc[1], 0, 0, 0); \
    acc[2] = __builtin_amdgcn_mfma_f32_16x16x32_bf16(af0, bf2, acc[2], 0, 0, 0); \
    acc[3] = __builtin_amdgcn_mfma_f32_16x16x32_bf16(af0, bf3, acc[3], 0, 0, 0); \
} while (0)

#define FENCE(n_) do {                                                        \
    asm volatile("s_waitcnt vmcnt(" #n_ ")" ::: "memory");                    \
    __builtin_amdgcn_sched_barrier(0);                                        \
    __builtin_amdgcn_s_barrier();                                             \
    __builtin_amdgcn_sched_barrier(0);                                        \
} while (0)

    STAGE(0, 0);
    STAGE(1, 1);
    FENCE(2);

    #pragma unroll 1
    for (int t = 0; t < 30; t += 3) {
        STAGE(2, t + 2); STEP(0); FENCE(2);
        STAGE(0, t + 3); STEP(1); FENCE(2);
        STAGE(1, t + 4); STEP(2); FENCE(2);
    }
    STEP(0);            // t=30
    FENCE(0);           // stage 31 complete
    STEP(1);            // t=31
    __syncthreads();    // all ring reads done; LDS free for Ys reuse

#undef STAGE
#undef STEP
#undef FENCE

    float bb[4];
    #pragma unroll
    for (int ni = 0; ni < 4; ++ni) bb[ni] = bias[wc + ni * 16 + col];

    ushort* Ys = (ushort*)As;           // 64x128 bf16 = 16 KB
    const int orow4 = (lane >> 4) * 4;
    #pragma unroll
    for (int ni = 0; ni < 4; ++ni)
        #pragma unroll
        for (int j = 0; j < 4; ++j) {
            float v = fmaxf(acc[ni][j] + bb[ni], 0.f);
            const int rl = wr + orow4 + j;
            const int cl = wc + ni * 16 + col;
            Ys[(rl * 128 + cl) ^ ((rl & 15) << 3)] = f2bf(v);
        }
    __syncthreads();

    {
        const int r = tid >> 3, c = (tid & 7) * 16;
        const int swz = (r & 15) << 3;
        ushort* Yg = Y + (size_t)(row0 + r) * 128 + c;
        *(uint4*)&Yg[0] = *(const uint4*)&Ys[(r * 128 + c)     ^ swz];
        *(uint4*)&Yg[8] = *(const uint4*)&Ys[(r * 128 + c + 8) ^ swz];
    }
}

// ---------------------------------------------------------------------------
// ktv: per (batch, 64-row chunk): partial Mt_part[v][e] = sum_r v[r][v]*k[r][e]
// ---------------------------------------------------------------------------
__global__ __launch_bounds__(256) void ktv_kernel(
    const ushort* __restrict__ kp, const ushort* __restrict__ vp,
    ushort* __restrict__ part)
{
    const int b = blockIdx.y, chunk = blockIdx.x;
    const ushort* K = kp + ((size_t)b * LK + chunk * 64) * 128;
    const ushort* V = vp + ((size_t)b * LK + chunk * 64) * 128;
    ushort* P = part + ((size_t)(b * 32 + chunk)) * 16384;

    __shared__ __align__(16) ushort ks[64 * 128];
    __shared__ __align__(16) ushort vs[64 * 128];
    const int t = threadIdx.x;
    {
        const int r = t >> 2, cc = (t & 3) * 32;
        #pragma unroll
        for (int j = 0; j < 4; ++j) {
            *(uint4*)&ks[r * 128 + cc + j * 8] = *(const uint4*)&K[r * 128 + cc + j * 8];
            *(uint4*)&vs[r * 128 + cc + j * 8] = *(const uint4*)&V[r * 128 + cc + j * 8];
        }
    }
    __syncthreads();

    const int e0 = (t & 15) * 8;
    const int v0 = (t >> 4) * 8;
    float acc[8][8];
    #pragma unroll
    for (int i = 0; i < 8; ++i)
        #pragma unroll
        for (int j = 0; j < 8; ++j) acc[i][j] = 0.f;

    for (int r = 0; r < 64; ++r) {
        uint4 kf = *(const uint4*)&ks[r * 128 + e0];
        uint4 vf = *(const uint4*)&vs[r * 128 + v0];
        const ushort* kw = (const ushort*)&kf;
        const ushort* vw = (const ushort*)&vf;
        float ke[8], ve[8];
        #pragma unroll
        for (int j = 0; j < 8; ++j) { ke[j] = bf2f(kw[j]); ve[j] = bf2f(vw[j]); }
        #pragma unroll
        for (int i = 0; i < 8; ++i)
            #pragma unroll
            for (int j = 0; j < 8; ++j)
                acc[i][j] = fmaf(ve[i], ke[j], acc[i][j]);
    }

    #pragma unroll
    for (int i = 0; i < 8; ++i) {
        ushort tmp[8];
        #pragma unroll
        for (int j = 0; j < 8; ++j) tmp[j] = f2bf(acc[i][j]);
        *(uint4*)&P[(v0 + i) * 128 + e0] = *(uint4*)&tmp[0];
    }
}

// ---------------------------------------------------------------------------
// reduce: Mt[b][v*128+e] = bf16(KSCALE * sum_{c<32} part[b][c][v*128+e])
// ---------------------------------------------------------------------------
__global__ __launch_bounds__(256) void reduce_kernel(
    const ushort* __restrict__ part, ushort* __restrict__ Mt)
{
    const int g = blockIdx.x * 256 + threadIdx.x;
    const int b = g >> 14, idx = g & 16383;
    const ushort* P = part + (size_t)b * 32 * 16384 + idx;
    float s = 0.f;
    #pragma unroll
    for (int c = 0; c < 32; ++c) s += bf2f(P[(size_t)c * 16384]);
    Mt[g] = f2bf(s * KSCALE);
}

// ---------------------------------------------------------------------------
// qm: out[row][v] = sum_e qp[row][e] * Mt[b][v][e]
// ---------------------------------------------------------------------------
__global__ __launch_bounds__(256) void qm_kernel(
    const ushort* __restrict__ qp, const ushort* __restrict__ Mt,
    float* __restrict__ out)
{
    const int row0 = blockIdx.x * 64;
    const int b = row0 >> 11;
    const ushort* Q = qp + (size_t)row0 * 128;
    const ushort* M = Mt + (size_t)b * 16384;

    __shared__ __align__(16) ushort As[64 * 128];
    __shared__ __align__(16) ushort Bs[128 * 128];

    const int t = threadIdx.x;
    {
        const int r = t >> 2, cc = (t & 3) * 32;
        const int swz = (r & 15) << 3;
        #pragma unroll
        for (int j = 0; j < 4; ++j)
            *(uint4*)&As[(r * 128 + cc + j * 8) ^ swz] = *(const uint4*)&Q[r * 128 + cc + j * 8];
    }
    {
        const int r = t >> 1, cc = (t & 1) * 64;
        const int swz = (r & 15) << 3;
        #pragma unroll
        for (int j = 0; j < 8; ++j)
            *(uint4*)&Bs[(r * 128 + cc + j * 8) ^ swz] = *(const uint4*)&M[r * 128 + cc + j * 8];
    }
    __syncthreads();

    const int lane = t & 63;
    const int wcol = (t >> 6) * 32;
    const int col  = lane & 15;
    const int kgrp = (lane >> 4) * 8;
    const int fswz = col << 3;

    f32x4 acc[4][2];
    #pragma unroll
    for (int mi = 0; mi < 4; ++mi)
        #pragma unroll
        for (int ni = 0; ni < 2; ++ni)
            acc[mi][ni] = (f32x4){0.f, 0.f, 0.f, 0.f};

    #pragma unroll
    for (int kk = 0; kk < 4; ++kk) {
        const int kb = kk * 32 + kgrp;
        short8 af[4], bfv[2];
        #pragma unroll
        for (int mi = 0; mi < 4; ++mi)
            af[mi] = *(const short8*)&As[((mi * 16 + col) * 128 + kb) ^ fswz];
        #pragma unroll
        for (int ni = 0; ni < 2; ++ni)
            bfv[ni] = *(const short8*)&Bs[((wcol + ni * 16 + col) * 128 + kb) ^ fswz];
        #pragma unroll
        for (int mi = 0; mi < 4; ++mi)
            #pragma unroll
            for (int ni = 0; ni < 2; ++ni)
                acc[mi][ni] = __builtin_amdgcn_mfma_f32_16x16x32_bf16(
                    af[mi], bfv[ni], acc[mi][ni], 0, 0, 0);
    }

    const int orow = (lane >> 4) * 4;
    #pragma unroll
    for (int mi = 0; mi < 4; ++mi)
        #pragma unroll
        for (int ni = 0; ni < 2; ++ni)
            #pragma unroll
            for (int j = 0; j < 4; ++j)
                out[(size_t)(row0 + mi * 16 + orow + j) * 128 + wcol + ni * 16 + col] =
                    acc[mi][ni][j];
}

// ---------------------------------------------------------------------------
extern "C" void kernel_launch(void* const* d_in, const int* in_sizes, int n_in,
                              void* d_out, int out_size, void* d_ws, size_t ws_size,
                              hipStream_t stream)
{
    const float* query = (const float*)d_in[0];
    const float* key   = (const float*)d_in[1];
    const float* value = (const float*)d_in[2];
    const float* Wq    = (const float*)d_in[3];
    const float* bq    = (const float*)d_in[4];
    const float* Wk    = (const float*)d_in[5];
    const float* bk    = (const float*)d_in[6];
    const float* Wv    = (const float*)d_in[7];
    const float* bv    = (const float*)d_in[8];
    float* out = (float*)d_out;

    ushort* qp   = (ushort*)d_ws;                    // 16384*128 bf16
    ushort* kp   = qp + (size_t)MROWS * 128;
    ushort* vp   = kp + (size_t)MROWS * 128;
    ushort* Wt   = vp + (size_t)MROWS * 128;         // 3*128*1024 bf16
    ushort* part = Wt + (size_t)3 * 128 * 1024;      // 8*32*16384 bf16
    ushort* Mt   = part + (size_t)8 * 32 * 16384;    // 8*16384 bf16

    prep_kernel<<<dim3(16, 2, 3), 256, 0, stream>>>(Wq, Wk, Wv, Wt);
    proj_kernel<<<dim3(256, 3), 512, 0, stream>>>(query, bq, key, bk, value, bv,
                                                  Wt, qp, kp, vp);
    ktv_kernel<<<dim3(32, NB), 256, 0, stream>>>(kp, vp, part);
    reduce_kernel<<<512, 256, 0, stream>>>(part, Mt);
    qm_kernel<<<MROWS / 64, 256, 0, stream>>>(qp, Mt, out);
}